// Round 7
// baseline (206.862 us; speedup 1.0000x reference)
//
#include <hip/hip_runtime.h>
#include <cstddef>

#define B_SZ 16
#define HW 1024
#define CCH 512
#define K_LEN 256
#define N_HEADS 8
#define EPS 1e-5f

typedef __bf16 bf16;
typedef bf16 bf16x8 __attribute__((ext_vector_type(8)));
typedef bf16 bf16x4 __attribute__((ext_vector_type(4)));
typedef float f32x4 __attribute__((ext_vector_type(4)));

// async global->LDS, 16B per lane; LDS dest is wave-uniform base + lane*16
__device__ __forceinline__ void gl_lds16(const bf16* g, bf16* l) {
    __builtin_amdgcn_global_load_lds(
        (const __attribute__((address_space(1))) void*)g,
        (__attribute__((address_space(3))) void*)l, 16, 0, 0);
}

// ---------------------------------------------------------------------------
// Merged prep: [0,2048)   transpose+cast img  [B][512][1024] f32 -> [B][1024][512] bf16
//              [2048,3072) cast audio f32 -> bf16
//              [3072,3328) transpose+cast weights -> wT[4][512][512] (n-major)
// ---------------------------------------------------------------------------
__global__ __launch_bounds__(256) void prep_kernel(
    const float* __restrict__ img, const float* __restrict__ audio,
    const float* __restrict__ Wq, const float* __restrict__ Wk,
    const float* __restrict__ Wv, const float* __restrict__ Wo,
    bf16* __restrict__ img_bf, bf16* __restrict__ aud_bf, bf16* __restrict__ wT)
{
    __shared__ bf16 T[64][72];
    const int bid = blockIdx.x;
    const int tid = threadIdx.x;

    if (bid < 2048) {
        // ---- transpose+cast img
        const int s0 = (bid & 15) * 64;
        const int c0 = ((bid >> 4) & 7) * 64;
        const int b  = bid >> 7;
        {
            const int r = tid >> 2, cs = (tid & 3) << 4;
            const float* sp = img + ((size_t)b * CCH + c0 + r) * HW + s0 + cs;
            #pragma unroll
            for (int i = 0; i < 4; ++i) {
                float4 f = *(const float4*)(sp + i * 4);
                T[r][cs + i*4 + 0] = (bf16)f.x;
                T[r][cs + i*4 + 1] = (bf16)f.y;
                T[r][cs + i*4 + 2] = (bf16)f.z;
                T[r][cs + i*4 + 3] = (bf16)f.w;
            }
        }
        __syncthreads();
        {
            const int ss = tid >> 2, ks = (tid & 3) << 4;
            bf16x8 a, b8;
            #pragma unroll
            for (int j = 0; j < 8; ++j) { a[j] = T[ks + j][ss]; b8[j] = T[ks + 8 + j][ss]; }
            bf16* dp = img_bf + ((size_t)b * HW + s0 + ss) * CCH + c0 + ks;
            *(bf16x8*)dp = a;
            *(bf16x8*)(dp + 8) = b8;
        }
    } else if (bid < 3072) {
        // ---- cast audio
        const size_t i = ((size_t)(bid - 2048) * 256 + tid) * 8;
        float4 a = *(const float4*)(audio + i);
        float4 b = *(const float4*)(audio + i + 4);
        bf16x8 o;
        o[0] = (bf16)a.x; o[1] = (bf16)a.y; o[2] = (bf16)a.z; o[3] = (bf16)a.w;
        o[4] = (bf16)b.x; o[5] = (bf16)b.y; o[6] = (bf16)b.z; o[7] = (bf16)b.w;
        *(bf16x8*)(aud_bf + i) = o;
    } else {
        // ---- transpose+cast weights
        const int b2 = bid - 3072;
        const int n0 = (b2 & 7) * 64;
        const int k0 = ((b2 >> 3) & 7) * 64;
        const int w  = b2 >> 6;
        const float* src = (w == 0) ? Wq : (w == 1) ? Wk : (w == 2) ? Wv : Wo;
        {
            const int r = tid >> 2, cs = (tid & 3) << 4;
            const float* sp = src + (size_t)(k0 + r) * CCH + n0 + cs;
            #pragma unroll
            for (int i = 0; i < 4; ++i) {
                float4 f = *(const float4*)(sp + i * 4);
                T[r][cs + i*4 + 0] = (bf16)f.x;
                T[r][cs + i*4 + 1] = (bf16)f.y;
                T[r][cs + i*4 + 2] = (bf16)f.z;
                T[r][cs + i*4 + 3] = (bf16)f.w;
            }
        }
        __syncthreads();
        {
            const int nn = tid >> 2, ks = (tid & 3) << 4;
            bf16x8 a, b8;
            #pragma unroll
            for (int j = 0; j < 8; ++j) { a[j] = T[ks + j][nn]; b8[j] = T[ks + 8 + j][nn]; }
            bf16* dp = wT + (size_t)w * CCH * CCH + (size_t)(n0 + nn) * CCH + k0 + ks;
            *(bf16x8*)dp = a;
            *(bf16x8*)(dp + 8) = b8;
        }
    }
}

// ---------------------------------------------------------------------------
// O-projection GEMM (proven R2 single-buffer schedule) with XCD-chunked
// block swizzle: 1D grid 512; g=bid>>5, r=bid&31 -> m=g*8+(r&7), n=r>>3.
// ---------------------------------------------------------------------------
__global__ __launch_bounds__(256) void gemm_bf16_mfma(
    const bf16* __restrict__ A, const bf16* __restrict__ Bt,
    const float* __restrict__ bias, bf16* __restrict__ out)
{
    const int bid  = blockIdx.x;
    const int g    = bid >> 5, rr = bid & 31;
    const int m0 = (g * 8 + (rr & 7)) * 128;
    const int n0 = (rr >> 3) * 128;
    const int tid  = threadIdx.x;
    const int wave = tid >> 6, lane = tid & 63;
    const int l15 = lane & 15, quad = lane >> 4;
    const int wm = (wave >> 1) * 64, wn = (wave & 1) * 64;

    __shared__ bf16 As[128 * 32];
    __shared__ bf16 Bs[128 * 32];

    const int r16 = lane >> 2;          // row within 16-row chunk
    const int ks  = (lane & 3) * 8;     // k-seg (8 elems = 16B)

    f32x4 acc[4][4];
    #pragma unroll
    for (int i = 0; i < 4; ++i)
        #pragma unroll
        for (int j = 0; j < 4; ++j)
            acc[i][j] = (f32x4){0.f, 0.f, 0.f, 0.f};

    for (int k0 = 0; k0 < 512; k0 += 32) {
        #pragma unroll
        for (int i = 0; i < 2; ++i) {
            const int c = wave * 2 + i;           // chunk 0..7 (16 rows each)
            gl_lds16(A  + (size_t)(m0 + c * 16 + r16) * 512 + k0 + ks, &As[c * 512]);
            gl_lds16(Bt + (size_t)(n0 + c * 16 + r16) * 512 + k0 + ks, &Bs[c * 512]);
        }
        __syncthreads();
        bf16x8 af[4], bfr[4];
        #pragma unroll
        for (int i = 0; i < 4; ++i)
            af[i] = *(const bf16x8*)&As[(wm + i * 16 + l15) * 32 + quad * 8];
        #pragma unroll
        for (int j = 0; j < 4; ++j)
            bfr[j] = *(const bf16x8*)&Bs[(wn + j * 16 + l15) * 32 + quad * 8];
        #pragma unroll
        for (int i = 0; i < 4; ++i)
            #pragma unroll
            for (int j = 0; j < 4; ++j)
                acc[i][j] = __builtin_amdgcn_mfma_f32_16x16x32_bf16(bfr[j], af[i], acc[i][j], 0, 0, 0);
        __syncthreads();
    }

    #pragma unroll
    for (int j = 0; j < 4; ++j) {
        const int gn = n0 + wn + j * 16 + quad * 4;
        const float4 bv4 = *(const float4*)(bias + gn);
        const float bb[4] = {bv4.x, bv4.y, bv4.z, bv4.w};
        #pragma unroll
        for (int i = 0; i < 4; ++i) {
            const int gm = m0 + wm + i * 16 + l15;
            bf16x4 ov;
            #pragma unroll
            for (int r = 0; r < 4; ++r) ov[r] = (bf16)(acc[i][j][r] + bb[r]);
            *(bf16x4*)(out + (size_t)gm * 512 + gn) = ov;
        }
    }
}

// ---------------------------------------------------------------------------
// Merged Q + KV GEMM dispatch: 768 blocks (3/CU), proven R2 single-buffer
// schedule, XCD-chunked swizzle on both halves.
// ---------------------------------------------------------------------------
__global__ __launch_bounds__(256) void qkv_gemm(
    const bf16* __restrict__ imgA, const bf16* __restrict__ WqT,
    const float* __restrict__ bq, bf16* __restrict__ qout,
    const bf16* __restrict__ audA, const bf16* __restrict__ WkvT,
    const float* __restrict__ bk, const float* __restrict__ bv,
    bf16* __restrict__ khout, bf16* __restrict__ vtout)
{
    const int bid  = blockIdx.x;
    const int tid  = threadIdx.x;
    const int wave = tid >> 6, lane = tid & 63;
    const int l15 = lane & 15, quad = lane >> 4;
    const int wm = (wave >> 1) * 64, wn = (wave & 1) * 64;

    __shared__ bf16 As[128 * 32];
    __shared__ bf16 Bs[128 * 32];

    const int r16 = lane >> 2;
    const int ks  = (lane & 3) * 8;

    f32x4 acc[4][4];
    #pragma unroll
    for (int i = 0; i < 4; ++i)
        #pragma unroll
        for (int j = 0; j < 4; ++j)
            acc[i][j] = (f32x4){0.f, 0.f, 0.f, 0.f};

    if (bid < 512) {
        // ---------------- Q projection: M=16384, N=512 ----------------
        const int g = bid >> 5, rr = bid & 31;
        const int m0 = (g * 8 + (rr & 7)) * 128;
        const int n0 = (rr >> 3) * 128;

        for (int k0 = 0; k0 < 512; k0 += 32) {
            #pragma unroll
            for (int i = 0; i < 2; ++i) {
                const int c = wave * 2 + i;
                gl_lds16(imgA + (size_t)(m0 + c * 16 + r16) * 512 + k0 + ks, &As[c * 512]);
                gl_lds16(WqT  + (size_t)(n0 + c * 16 + r16) * 512 + k0 + ks, &Bs[c * 512]);
            }
            __syncthreads();
            bf16x8 af[4], bfr[4];
            #pragma unroll
            for (int i = 0; i < 4; ++i)
                af[i] = *(const bf16x8*)&As[(wm + i * 16 + l15) * 32 + quad * 8];
            #pragma unroll
            for (int j = 0; j < 4; ++j)
                bfr[j] = *(const bf16x8*)&Bs[(wn + j * 16 + l15) * 32 + quad * 8];
            #pragma unroll
            for (int i = 0; i < 4; ++i)
                #pragma unroll
                for (int j = 0; j < 4; ++j)
                    acc[i][j] = __builtin_amdgcn_mfma_f32_16x16x32_bf16(bfr[j], af[i], acc[i][j], 0, 0, 0);
            __syncthreads();
        }

        #pragma unroll
        for (int j = 0; j < 4; ++j) {
            const int gn = n0 + wn + j * 16 + quad * 4;
            const float4 bv4 = *(const float4*)(bq + gn);
            const float bb[4] = {bv4.x, bv4.y, bv4.z, bv4.w};
            #pragma unroll
            for (int i = 0; i < 4; ++i) {
                const int gm = m0 + wm + i * 16 + l15;
                bf16x4 ov;
                #pragma unroll
                for (int r = 0; r < 4; ++r) ov[r] = (bf16)(acc[i][j][r] + bb[r]);
                *(bf16x4*)(qout + (size_t)gm * 512 + gn) = ov;
            }
        }
    } else {
        // ---------------- K|V: M=4096, N=1024 ----------------
        const int b2 = bid - 512;
        const int g = b2 >> 6, rr = b2 & 63;
        const int m0 = (g * 8 + (rr & 7)) * 128;
        const int n0 = (rr >> 3) * 128;

        for (int k0 = 0; k0 < 512; k0 += 32) {
            #pragma unroll
            for (int i = 0; i < 2; ++i) {
                const int c = wave * 2 + i;
                gl_lds16(audA + (size_t)(m0 + c * 16 + r16) * 512 + k0 + ks, &As[c * 512]);
                gl_lds16(WkvT + (size_t)(n0 + c * 16 + r16) * 512 + k0 + ks, &Bs[c * 512]);
            }
            __syncthreads();
            bf16x8 af[4], bfr[4];
            #pragma unroll
            for (int i = 0; i < 4; ++i)
                af[i] = *(const bf16x8*)&As[(wm + i * 16 + l15) * 32 + quad * 8];
            #pragma unroll
            for (int j = 0; j < 4; ++j)
                bfr[j] = *(const bf16x8*)&Bs[(wn + j * 16 + l15) * 32 + quad * 8];
            #pragma unroll
            for (int i = 0; i < 4; ++i)
                #pragma unroll
                for (int j = 0; j < 4; ++j)
                    acc[i][j] = __builtin_amdgcn_mfma_f32_16x16x32_bf16(af[i], bfr[j], acc[i][j], 0, 0, 0);
            __syncthreads();
        }

        #pragma unroll
        for (int j = 0; j < 4; ++j) {
            const int gn = n0 + wn + j * 16 + l15;
            if (gn < 512) {
                const int h = gn >> 6, d = gn & 63;
                const float bias = bk[gn];
                #pragma unroll
                for (int i = 0; i < 4; ++i) {
                    const int gm = m0 + wm + i * 16 + quad * 4;
                    const int b = gm >> 8, key = gm & 255;
                    bf16* base = khout + ((((size_t)b * N_HEADS + h) * K_LEN) + key) * 64 + d;
                    #pragma unroll
                    for (int r = 0; r < 4; ++r)
                        base[(size_t)r * 64] = (bf16)(acc[i][j][r] + bias);
                }
            } else {
                const int ch = gn - 512;
                const int h = ch >> 6, d = ch & 63;
                const float bias = bv[ch];
                #pragma unroll
                for (int i = 0; i < 4; ++i) {
                    const int gm = m0 + wm + i * 16 + quad * 4;
                    const int b = gm >> 8, key = gm & 255;
                    bf16x4 pk;
                    #pragma unroll
                    for (int r = 0; r < 4; ++r) pk[r] = (bf16)(acc[i][j][r] + bias);
                    *(bf16x4*)(vtout + (((size_t)b * N_HEADS + h) * 64 + d) * K_LEN + key) = pk;
                }
            }
        }
    }
}

// ---------------------------------------------------------------------------
// MFMA attention: S^T trick + exact softmax + Vt@Pt.
// V is NOT LDS-staged: per-(b,h) V (32 KB) is L2-resident (16 consecutive
// blocks on one XCD share it — R6 chunking), so PV reads 16B fragments
// straight from global vt[b][h][d][256] (m169 pattern: skip staging when
// L2-fit). LDS drops 70.7 -> 36.9 KB => 4 blocks/CU (16 waves/CU, was 8).
//   xcd = bid&7; idx = bid>>3; bh = xcd + 8*(idx>>4); sblk = idx&15.
// ---------------------------------------------------------------------------
__global__ __launch_bounds__(256) void attn_mfma(
    const bf16* __restrict__ q,    // [B*1024][512]
    const bf16* __restrict__ kh,   // [B][H][256][64]
    const bf16* __restrict__ vt,   // [B][H][64][256]
    bf16* __restrict__ o)          // [B*1024][512]
{
    const int bid = blockIdx.x;
    const int xcd = bid & 7, idx = bid >> 3;
    const int bh  = xcd + 8 * (idx >> 4);
    const int s0  = (idx & 15) * 64;
    const int tid = threadIdx.x;
    const int wave = tid >> 6, lane = tid & 63;
    const int l15 = lane & 15, quad = lane >> 4;
    const int b = bh >> 3, h = bh & 7;

    __shared__ bf16 KsPt[18432];   // Ks [256][72]; later Pt: 4 waves x [16][264]

    const bf16* khb = kh + (size_t)bh * K_LEN * 64;
    const bf16* vtb = vt + (size_t)bh * 64 * K_LEN;

    #pragma unroll
    for (int i = 0; i < 8; ++i) {
        const int chunk = tid + (i << 8);
        const int key = chunk >> 3, dseg = (chunk & 7) << 3;
        *(bf16x8*)&KsPt[key * 72 + dseg] = *(const bf16x8*)(khb + key * 64 + dseg);
    }
    __syncthreads();

    const int qrow = s0 + wave * 16 + l15;
    const bf16* qp = q + ((size_t)(b * HW + qrow)) * 512 + h * 64 + quad * 8;
    const bf16x8 qf0 = *(const bf16x8*)qp;
    const bf16x8 qf1 = *(const bf16x8*)(qp + 32);

    f32x4 acc[16];
    #pragma unroll
    for (int m = 0; m < 16; ++m) acc[m] = (f32x4){0.f, 0.f, 0.f, 0.f};
    #pragma unroll
    for (int m = 0; m < 16; ++m) {
        const bf16x8 a0 = *(const bf16x8*)&KsPt[(m * 16 + l15) * 72 + quad * 8];
        const bf16x8 a1 = *(const bf16x8*)&KsPt[(m * 16 + l15) * 72 + 32 + quad * 8];
        acc[m] = __builtin_amdgcn_mfma_f32_16x16x32_bf16(a0, qf0, acc[m], 0, 0, 0);
        acc[m] = __builtin_amdgcn_mfma_f32_16x16x32_bf16(a1, qf1, acc[m], 0, 0, 0);
    }

    float mx = -1e30f;
    #pragma unroll
    for (int m = 0; m < 16; ++m)
        mx = fmaxf(mx, fmaxf(fmaxf(acc[m][0], acc[m][1]), fmaxf(acc[m][2], acc[m][3])));
    mx = fmaxf(mx, __shfl_xor(mx, 16, 64));
    mx = fmaxf(mx, __shfl_xor(mx, 32, 64));

    __syncthreads();                 // all waves done reading Ks before Pt overwrite

    bf16* PtW = &KsPt[wave * 4224];
    float l_sum = 0.f;
    #pragma unroll
    for (int m = 0; m < 16; ++m) {
        bf16x4 pk;
        #pragma unroll
        for (int r = 0; r < 4; ++r) {
            const float p = __expf((acc[m][r] - mx) * 0.125f);
            l_sum += p;
            pk[r] = (bf16)p;
        }
        *(bf16x4*)&PtW[l15 * 264 + m * 16 + quad * 4] = pk;
    }
    l_sum += __shfl_xor(l_sum, 16, 64);
    l_sum += __shfl_xor(l_sum, 32, 64);

    f32x4 oacc[4];
    #pragma unroll
    for (int m = 0; m < 4; ++m) oacc[m] = (f32x4){0.f, 0.f, 0.f, 0.f};
    #pragma unroll
    for (int s = 0; s < 8; ++s) {
        const bf16x8 pb = *(const bf16x8*)&PtW[l15 * 264 + s * 32 + quad * 8];
        #pragma unroll
        for (int m = 0; m < 4; ++m) {
            const bf16x8 va = *(const bf16x8*)(vtb + (size_t)(m * 16 + l15) * 256 + s * 32 + quad * 8);
            oacc[m] = __builtin_amdgcn_mfma_f32_16x16x32_bf16(va, pb, oacc[m], 0, 0, 0);
        }
    }

    const float inv = 1.0f / l_sum;
    bf16* op = o + ((size_t)(b * HW + qrow)) * 512 + h * 64 + quad * 4;
    #pragma unroll
    for (int m = 0; m < 4; ++m) {
        bf16x4 ov;
        #pragma unroll
        for (int r = 0; r < 4; ++r) ov[r] = (bf16)(oacc[m][r] * inv);
        *(bf16x4*)&op[m * 16] = ov;
    }
}

// ---------------------------------------------------------------------------
// Residual + LayerNorm + transpose, single global read.
// ---------------------------------------------------------------------------
__global__ __launch_bounds__(256) void ln_kernel(
    const bf16* __restrict__ proj, const bf16* __restrict__ imgb,
    const float* __restrict__ gamma, const float* __restrict__ beta,
    float* __restrict__ out)
{
    const int b  = blockIdx.y;
    const int s0 = blockIdx.x * 32;
    const int tid = threadIdx.x;
    const int wave = tid >> 6, lane = tid & 63;

    __shared__ float Y[32][513];

    const int cb = lane * 8;
    const float4 g0 = *(const float4*)(gamma + cb);
    const float4 g1 = *(const float4*)(gamma + cb + 4);
    const float4 b0 = *(const float4*)(beta + cb);
    const float4 b1 = *(const float4*)(beta + cb + 4);
    const float gg[8] = {g0.x, g0.y, g0.z, g0.w, g1.x, g1.y, g1.z, g1.w};
    const float bb[8] = {b0.x, b0.y, b0.z, b0.w, b1.x, b1.y, b1.z, b1.w};

    #pragma unroll
    for (int rr = 0; rr < 8; ++rr) {
        const int ss = wave * 8 + rr;
        const size_t row = (size_t)b * HW + s0 + ss;
        bf16x8 p8 = *(const bf16x8*)(proj + row * 512 + cb);
        bf16x8 i8 = *(const bf16x8*)(imgb + row * 512 + cb);
        float y[8];
        float sum = 0.f, sq = 0.f;
        #pragma unroll
        for (int j = 0; j < 8; ++j) {
            y[j] = (float)p8[j] + (float)i8[j];
            sum += y[j]; sq += y[j] * y[j];
        }
        #pragma unroll
        for (int off = 32; off > 0; off >>= 1) {
            sum += __shfl_xor(sum, off, 64);
            sq  += __shfl_xor(sq, off, 64);
        }
        const float mu = sum * (1.f / 512.f);
        const float rs = rsqrtf(sq * (1.f / 512.f) - mu * mu + EPS);
        #pragma unroll
        for (int j = 0; j < 8; ++j)
            Y[ss][cb + j] = (y[j] - mu) * rs * gg[j] + bb[j];
    }
    __syncthreads();

    #pragma unroll
    for (int it = 0; it < 16; ++it) {
        const int idx = it * 256 + tid;      // 0..4095
        const int c = idx >> 3, sseg = (idx & 7) << 2;
        float4 o4;
        o4.x = Y[sseg + 0][c];
        o4.y = Y[sseg + 1][c];
        o4.z = Y[sseg + 2][c];
        o4.w = Y[sseg + 3][c];
        *(float4*)(out + ((size_t)b * CCH + c) * HW + s0 + sseg) = o4;
    }
}

// ---------------------------------------------------------------------------
extern "C" void kernel_launch(void* const* d_in, const int* in_sizes, int n_in,
                              void* d_out, int out_size, void* d_ws, size_t ws_size,
                              hipStream_t stream) {
    const float* img   = (const float*)d_in[0];
    const float* audio = (const float*)d_in[1];
    const float* Wq    = (const float*)d_in[2];
    const float* bq    = (const float*)d_in[3];
    const float* Wk    = (const float*)d_in[4];
    const float* bk    = (const float*)d_in[5];
    const float* Wv    = (const float*)d_in[6];
    const float* bv    = (const float*)d_in[7];
    const float* Wo    = (const float*)d_in[8];
    const float* bo    = (const float*)d_in[9];
    const float* gamma = (const float*)d_in[10];
    const float* beta  = (const float*)d_in[11];

    bf16* wsb    = (bf16*)d_ws;
    bf16* img_bf = wsb;                     // 8388608
    bf16* aud_bf = img_bf + 8388608;        // 2097152
    bf16* wT     = aud_bf + 2097152;        // 4*262144 (q,k,v,o)
    bf16* q_bf   = wT + 1048576;            // 8388608
    bf16* kh_bf  = q_bf + 8388608;          // 2097152  [B][H][256][64]
    bf16* vt_bf  = kh_bf + 2097152;         // 2097152  [B][H][64][256]
    bf16* a_bf   = vt_bf + 2097152;         // 8388608
    bf16* p_bf   = q_bf;                    // alias: q dead after attention

    // 1. All casts/transposes in one dispatch
    prep_kernel<<<dim3(3328), 256, 0, stream>>>(img, audio, Wq, Wk, Wv, Wo,
                                                img_bf, aud_bf, wT);
    // 2. Q + K + V projections in one 768-block dispatch (3 blocks/CU)
    qkv_gemm<<<dim3(768), 256, 0, stream>>>(img_bf, wT, bq, q_bf,
                                            aud_bf, wT + 262144, bk, bv, kh_bf, vt_bf);
    // 3. MFMA attention (XCD-chunked block order, V read from L2)
    attn_mfma<<<dim3(B_SZ * N_HEADS * (HW / 64)), 256, 0, stream>>>(q_bf, kh_bf, vt_bf, a_bf);
    // 4. Output projection: M=16384, N=512 (XCD-chunked block order)
    gemm_bf16_mfma<<<dim3(512), 256, 0, stream>>>(a_bf, wT + 3 * 262144, bo, p_bf);
    // 5. Residual + LN + transpose
    ln_kernel<<<dim3(32, 16), 256, 0, stream>>>(p_bf, img_bf, gamma, beta, (float*)d_out);
}

// Round 8
// 184.252 us; speedup vs baseline: 1.1227x; 1.1227x over previous
//
#include <hip/hip_runtime.h>
#include <cstddef>

#define B_SZ 16
#define HW 1024
#define CCH 512
#define K_LEN 256
#define N_HEADS 8
#define EPS 1e-5f

typedef __bf16 bf16;
typedef bf16 bf16x8 __attribute__((ext_vector_type(8)));
typedef bf16 bf16x4 __attribute__((ext_vector_type(4)));
typedef float f32x4 __attribute__((ext_vector_type(4)));

// async global->LDS, 16B per lane; LDS dest is wave-uniform base + lane*16
__device__ __forceinline__ void gl_lds16(const bf16* g, bf16* l) {
    __builtin_amdgcn_global_load_lds(
        (const __attribute__((address_space(1))) void*)g,
        (__attribute__((address_space(3))) void*)l, 16, 0, 0);
}

// ---------------------------------------------------------------------------
// Merged prep: [0,2048)   transpose+cast img  [B][512][1024] f32 -> [B][1024][512] bf16
//              [2048,3072) cast audio f32 -> bf16
//              [3072,3328) transpose+cast weights -> wT[4][512][512] (n-major)
// ---------------------------------------------------------------------------
__global__ __launch_bounds__(256) void prep_kernel(
    const float* __restrict__ img, const float* __restrict__ audio,
    const float* __restrict__ Wq, const float* __restrict__ Wk,
    const float* __restrict__ Wv, const float* __restrict__ Wo,
    bf16* __restrict__ img_bf, bf16* __restrict__ aud_bf, bf16* __restrict__ wT)
{
    __shared__ bf16 T[64][72];
    const int bid = blockIdx.x;
    const int tid = threadIdx.x;

    if (bid < 2048) {
        // ---- transpose+cast img
        const int s0 = (bid & 15) * 64;
        const int c0 = ((bid >> 4) & 7) * 64;
        const int b  = bid >> 7;
        {
            const int r = tid >> 2, cs = (tid & 3) << 4;
            const float* sp = img + ((size_t)b * CCH + c0 + r) * HW + s0 + cs;
            #pragma unroll
            for (int i = 0; i < 4; ++i) {
                float4 f = *(const float4*)(sp + i * 4);
                T[r][cs + i*4 + 0] = (bf16)f.x;
                T[r][cs + i*4 + 1] = (bf16)f.y;
                T[r][cs + i*4 + 2] = (bf16)f.z;
                T[r][cs + i*4 + 3] = (bf16)f.w;
            }
        }
        __syncthreads();
        {
            const int ss = tid >> 2, ks = (tid & 3) << 4;
            bf16x8 a, b8;
            #pragma unroll
            for (int j = 0; j < 8; ++j) { a[j] = T[ks + j][ss]; b8[j] = T[ks + 8 + j][ss]; }
            bf16* dp = img_bf + ((size_t)b * HW + s0 + ss) * CCH + c0 + ks;
            *(bf16x8*)dp = a;
            *(bf16x8*)(dp + 8) = b8;
        }
    } else if (bid < 3072) {
        // ---- cast audio
        const size_t i = ((size_t)(bid - 2048) * 256 + tid) * 8;
        float4 a = *(const float4*)(audio + i);
        float4 b = *(const float4*)(audio + i + 4);
        bf16x8 o;
        o[0] = (bf16)a.x; o[1] = (bf16)a.y; o[2] = (bf16)a.z; o[3] = (bf16)a.w;
        o[4] = (bf16)b.x; o[5] = (bf16)b.y; o[6] = (bf16)b.z; o[7] = (bf16)b.w;
        *(bf16x8*)(aud_bf + i) = o;
    } else {
        // ---- transpose+cast weights
        const int b2 = bid - 3072;
        const int n0 = (b2 & 7) * 64;
        const int k0 = ((b2 >> 3) & 7) * 64;
        const int w  = b2 >> 6;
        const float* src = (w == 0) ? Wq : (w == 1) ? Wk : (w == 2) ? Wv : Wo;
        {
            const int r = tid >> 2, cs = (tid & 3) << 4;
            const float* sp = src + (size_t)(k0 + r) * CCH + n0 + cs;
            #pragma unroll
            for (int i = 0; i < 4; ++i) {
                float4 f = *(const float4*)(sp + i * 4);
                T[r][cs + i*4 + 0] = (bf16)f.x;
                T[r][cs + i*4 + 1] = (bf16)f.y;
                T[r][cs + i*4 + 2] = (bf16)f.z;
                T[r][cs + i*4 + 3] = (bf16)f.w;
            }
        }
        __syncthreads();
        {
            const int nn = tid >> 2, ks = (tid & 3) << 4;
            bf16x8 a, b8;
            #pragma unroll
            for (int j = 0; j < 8; ++j) { a[j] = T[ks + j][nn]; b8[j] = T[ks + 8 + j][nn]; }
            bf16* dp = wT + (size_t)w * CCH * CCH + (size_t)(n0 + nn) * CCH + k0 + ks;
            *(bf16x8*)dp = a;
            *(bf16x8*)(dp + 8) = b8;
        }
    }
}

// ---------------------------------------------------------------------------
// O-projection GEMM (proven R2 single-buffer schedule) with XCD-chunked
// block swizzle: 1D grid 512; g=bid>>5, r=bid&31 -> m=g*8+(r&7), n=r>>3.
// ---------------------------------------------------------------------------
__global__ __launch_bounds__(256) void gemm_bf16_mfma(
    const bf16* __restrict__ A, const bf16* __restrict__ Bt,
    const float* __restrict__ bias, bf16* __restrict__ out)
{
    const int bid  = blockIdx.x;
    const int g    = bid >> 5, rr = bid & 31;
    const int m0 = (g * 8 + (rr & 7)) * 128;
    const int n0 = (rr >> 3) * 128;
    const int tid  = threadIdx.x;
    const int wave = tid >> 6, lane = tid & 63;
    const int l15 = lane & 15, quad = lane >> 4;
    const int wm = (wave >> 1) * 64, wn = (wave & 1) * 64;

    __shared__ bf16 As[128 * 32];
    __shared__ bf16 Bs[128 * 32];

    const int r16 = lane >> 2;          // row within 16-row chunk
    const int ks  = (lane & 3) * 8;     // k-seg (8 elems = 16B)

    f32x4 acc[4][4];
    #pragma unroll
    for (int i = 0; i < 4; ++i)
        #pragma unroll
        for (int j = 0; j < 4; ++j)
            acc[i][j] = (f32x4){0.f, 0.f, 0.f, 0.f};

    for (int k0 = 0; k0 < 512; k0 += 32) {
        #pragma unroll
        for (int i = 0; i < 2; ++i) {
            const int c = wave * 2 + i;           // chunk 0..7 (16 rows each)
            gl_lds16(A  + (size_t)(m0 + c * 16 + r16) * 512 + k0 + ks, &As[c * 512]);
            gl_lds16(Bt + (size_t)(n0 + c * 16 + r16) * 512 + k0 + ks, &Bs[c * 512]);
        }
        __syncthreads();
        bf16x8 af[4], bfr[4];
        #pragma unroll
        for (int i = 0; i < 4; ++i)
            af[i] = *(const bf16x8*)&As[(wm + i * 16 + l15) * 32 + quad * 8];
        #pragma unroll
        for (int j = 0; j < 4; ++j)
            bfr[j] = *(const bf16x8*)&Bs[(wn + j * 16 + l15) * 32 + quad * 8];
        #pragma unroll
        for (int i = 0; i < 4; ++i)
            #pragma unroll
            for (int j = 0; j < 4; ++j)
                acc[i][j] = __builtin_amdgcn_mfma_f32_16x16x32_bf16(bfr[j], af[i], acc[i][j], 0, 0, 0);
        __syncthreads();
    }

    #pragma unroll
    for (int j = 0; j < 4; ++j) {
        const int gn = n0 + wn + j * 16 + quad * 4;
        const float4 bv4 = *(const float4*)(bias + gn);
        const float bb[4] = {bv4.x, bv4.y, bv4.z, bv4.w};
        #pragma unroll
        for (int i = 0; i < 4; ++i) {
            const int gm = m0 + wm + i * 16 + l15;
            bf16x4 ov;
            #pragma unroll
            for (int r = 0; r < 4; ++r) ov[r] = (bf16)(acc[i][j][r] + bb[r]);
            *(bf16x4*)(out + (size_t)gm * 512 + gn) = ov;
        }
    }
}

// ---------------------------------------------------------------------------
// Merged Q + KV GEMM dispatch: 768 blocks (3/CU), proven R2 single-buffer
// schedule, XCD-chunked swizzle on both halves.
// ---------------------------------------------------------------------------
__global__ __launch_bounds__(256) void qkv_gemm(
    const bf16* __restrict__ imgA, const bf16* __restrict__ WqT,
    const float* __restrict__ bq, bf16* __restrict__ qout,
    const bf16* __restrict__ audA, const bf16* __restrict__ WkvT,
    const float* __restrict__ bk, const float* __restrict__ bv,
    bf16* __restrict__ khout, bf16* __restrict__ vtout)
{
    const int bid  = blockIdx.x;
    const int tid  = threadIdx.x;
    const int wave = tid >> 6, lane = tid & 63;
    const int l15 = lane & 15, quad = lane >> 4;
    const int wm = (wave >> 1) * 64, wn = (wave & 1) * 64;

    __shared__ bf16 As[128 * 32];
    __shared__ bf16 Bs[128 * 32];

    const int r16 = lane >> 2;
    const int ks  = (lane & 3) * 8;

    f32x4 acc[4][4];
    #pragma unroll
    for (int i = 0; i < 4; ++i)
        #pragma unroll
        for (int j = 0; j < 4; ++j)
            acc[i][j] = (f32x4){0.f, 0.f, 0.f, 0.f};

    if (bid < 512) {
        // ---------------- Q projection: M=16384, N=512 ----------------
        const int g = bid >> 5, rr = bid & 31;
        const int m0 = (g * 8 + (rr & 7)) * 128;
        const int n0 = (rr >> 3) * 128;

        for (int k0 = 0; k0 < 512; k0 += 32) {
            #pragma unroll
            for (int i = 0; i < 2; ++i) {
                const int c = wave * 2 + i;
                gl_lds16(imgA + (size_t)(m0 + c * 16 + r16) * 512 + k0 + ks, &As[c * 512]);
                gl_lds16(WqT  + (size_t)(n0 + c * 16 + r16) * 512 + k0 + ks, &Bs[c * 512]);
            }
            __syncthreads();
            bf16x8 af[4], bfr[4];
            #pragma unroll
            for (int i = 0; i < 4; ++i)
                af[i] = *(const bf16x8*)&As[(wm + i * 16 + l15) * 32 + quad * 8];
            #pragma unroll
            for (int j = 0; j < 4; ++j)
                bfr[j] = *(const bf16x8*)&Bs[(wn + j * 16 + l15) * 32 + quad * 8];
            #pragma unroll
            for (int i = 0; i < 4; ++i)
                #pragma unroll
                for (int j = 0; j < 4; ++j)
                    acc[i][j] = __builtin_amdgcn_mfma_f32_16x16x32_bf16(bfr[j], af[i], acc[i][j], 0, 0, 0);
            __syncthreads();
        }

        #pragma unroll
        for (int j = 0; j < 4; ++j) {
            const int gn = n0 + wn + j * 16 + quad * 4;
            const float4 bv4 = *(const float4*)(bq + gn);
            const float bb[4] = {bv4.x, bv4.y, bv4.z, bv4.w};
            #pragma unroll
            for (int i = 0; i < 4; ++i) {
                const int gm = m0 + wm + i * 16 + l15;
                bf16x4 ov;
                #pragma unroll
                for (int r = 0; r < 4; ++r) ov[r] = (bf16)(acc[i][j][r] + bb[r]);
                *(bf16x4*)(qout + (size_t)gm * 512 + gn) = ov;
            }
        }
    } else {
        // ---------------- K|V: M=4096, N=1024 ----------------
        const int b2 = bid - 512;
        const int g = b2 >> 6, rr = b2 & 63;
        const int m0 = (g * 8 + (rr & 7)) * 128;
        const int n0 = (rr >> 3) * 128;

        for (int k0 = 0; k0 < 512; k0 += 32) {
            #pragma unroll
            for (int i = 0; i < 2; ++i) {
                const int c = wave * 2 + i;
                gl_lds16(audA + (size_t)(m0 + c * 16 + r16) * 512 + k0 + ks, &As[c * 512]);
                gl_lds16(WkvT + (size_t)(n0 + c * 16 + r16) * 512 + k0 + ks, &Bs[c * 512]);
            }
            __syncthreads();
            bf16x8 af[4], bfr[4];
            #pragma unroll
            for (int i = 0; i < 4; ++i)
                af[i] = *(const bf16x8*)&As[(wm + i * 16 + l15) * 32 + quad * 8];
            #pragma unroll
            for (int j = 0; j < 4; ++j)
                bfr[j] = *(const bf16x8*)&Bs[(wn + j * 16 + l15) * 32 + quad * 8];
            #pragma unroll
            for (int i = 0; i < 4; ++i)
                #pragma unroll
                for (int j = 0; j < 4; ++j)
                    acc[i][j] = __builtin_amdgcn_mfma_f32_16x16x32_bf16(af[i], bfr[j], acc[i][j], 0, 0, 0);
            __syncthreads();
        }

        #pragma unroll
        for (int j = 0; j < 4; ++j) {
            const int gn = n0 + wn + j * 16 + l15;
            if (gn < 512) {
                const int h = gn >> 6, d = gn & 63;
                const float bias = bk[gn];
                #pragma unroll
                for (int i = 0; i < 4; ++i) {
                    const int gm = m0 + wm + i * 16 + quad * 4;
                    const int b = gm >> 8, key = gm & 255;
                    bf16* base = khout + ((((size_t)b * N_HEADS + h) * K_LEN) + key) * 64 + d;
                    #pragma unroll
                    for (int r = 0; r < 4; ++r)
                        base[(size_t)r * 64] = (bf16)(acc[i][j][r] + bias);
                }
            } else {
                const int ch = gn - 512;
                const int h = ch >> 6, d = ch & 63;
                const float bias = bv[ch];
                #pragma unroll
                for (int i = 0; i < 4; ++i) {
                    const int gm = m0 + wm + i * 16 + quad * 4;
                    const int b = gm >> 8, key = gm & 255;
                    bf16x4 pk;
                    #pragma unroll
                    for (int r = 0; r < 4; ++r) pk[r] = (bf16)(acc[i][j][r] + bias);
                    *(bf16x4*)(vtout + (((size_t)b * N_HEADS + h) * 64 + d) * K_LEN + key) = pk;
                }
            }
        }
    }
}

// ---------------------------------------------------------------------------
// MFMA attention (R6 staged-V version + two micro-fixes):
//   - post-Pt barrier removed: PtW regions are per-wave-private and same-wave
//     LDS ops are ordered; Vs is read-only after staging.
//   - s_setprio(1) around the two MFMA clusters (T5; independent blocks at
//     different phases co-reside 2/CU -> m191 regime, not m190 lockstep).
//   xcd = bid&7; idx = bid>>3; bh = xcd + 8*(idx>>4); sblk = idx&15.
// ---------------------------------------------------------------------------
__global__ __launch_bounds__(256) void attn_mfma(
    const bf16* __restrict__ q,    // [B*1024][512]
    const bf16* __restrict__ kh,   // [B][H][256][64]
    const bf16* __restrict__ vt,   // [B][H][64][256]
    bf16* __restrict__ o)          // [B*1024][512]
{
    const int bid = blockIdx.x;
    const int xcd = bid & 7, idx = bid >> 3;
    const int bh  = xcd + 8 * (idx >> 4);
    const int s0  = (idx & 15) * 64;
    const int tid = threadIdx.x;
    const int wave = tid >> 6, lane = tid & 63;
    const int l15 = lane & 15, quad = lane >> 4;
    const int b = bh >> 3, h = bh & 7;

    __shared__ bf16 KsPt[18432];   // Ks [256][72]; later Pt: 4 waves x [16][264]
    __shared__ bf16 Vs[16896];     // Vt [64][264]

    const bf16* khb = kh + (size_t)bh * K_LEN * 64;
    const bf16* vtb = vt + (size_t)bh * 64 * K_LEN;

    #pragma unroll
    for (int i = 0; i < 8; ++i) {
        const int chunk = tid + (i << 8);
        const int key = chunk >> 3, dseg = (chunk & 7) << 3;
        *(bf16x8*)&KsPt[key * 72 + dseg] = *(const bf16x8*)(khb + key * 64 + dseg);
        const int d = chunk >> 5, kseg = (chunk & 31) << 3;
        *(bf16x8*)&Vs[d * 264 + kseg] = *(const bf16x8*)(vtb + d * 256 + kseg);
    }
    __syncthreads();

    const int qrow = s0 + wave * 16 + l15;
    const bf16* qp = q + ((size_t)(b * HW + qrow)) * 512 + h * 64 + quad * 8;
    const bf16x8 qf0 = *(const bf16x8*)qp;
    const bf16x8 qf1 = *(const bf16x8*)(qp + 32);

    f32x4 acc[16];
    #pragma unroll
    for (int m = 0; m < 16; ++m) acc[m] = (f32x4){0.f, 0.f, 0.f, 0.f};
    __builtin_amdgcn_s_setprio(1);
    #pragma unroll
    for (int m = 0; m < 16; ++m) {
        const bf16x8 a0 = *(const bf16x8*)&KsPt[(m * 16 + l15) * 72 + quad * 8];
        const bf16x8 a1 = *(const bf16x8*)&KsPt[(m * 16 + l15) * 72 + 32 + quad * 8];
        acc[m] = __builtin_amdgcn_mfma_f32_16x16x32_bf16(a0, qf0, acc[m], 0, 0, 0);
        acc[m] = __builtin_amdgcn_mfma_f32_16x16x32_bf16(a1, qf1, acc[m], 0, 0, 0);
    }
    __builtin_amdgcn_s_setprio(0);

    float mx = -1e30f;
    #pragma unroll
    for (int m = 0; m < 16; ++m)
        mx = fmaxf(mx, fmaxf(fmaxf(acc[m][0], acc[m][1]), fmaxf(acc[m][2], acc[m][3])));
    mx = fmaxf(mx, __shfl_xor(mx, 16, 64));
    mx = fmaxf(mx, __shfl_xor(mx, 32, 64));

    __syncthreads();               // all waves done reading Ks before Pt overwrite

    bf16* PtW = &KsPt[wave * 4224];
    float l_sum = 0.f;
    #pragma unroll
    for (int m = 0; m < 16; ++m) {
        bf16x4 pk;
        #pragma unroll
        for (int r = 0; r < 4; ++r) {
            const float p = __expf((acc[m][r] - mx) * 0.125f);
            l_sum += p;
            pk[r] = (bf16)p;
        }
        *(bf16x4*)&PtW[l15 * 264 + m * 16 + quad * 4] = pk;
    }
    l_sum += __shfl_xor(l_sum, 16, 64);
    l_sum += __shfl_xor(l_sum, 32, 64);
    // no barrier: PtW is wave-private, same-wave LDS ops are ordered; Vs read-only

    f32x4 oacc[4];
    #pragma unroll
    for (int m = 0; m < 4; ++m) oacc[m] = (f32x4){0.f, 0.f, 0.f, 0.f};
    __builtin_amdgcn_s_setprio(1);
    #pragma unroll
    for (int s = 0; s < 8; ++s) {
        const bf16x8 pb = *(const bf16x8*)&PtW[l15 * 264 + s * 32 + quad * 8];
        #pragma unroll
        for (int m = 0; m < 4; ++m) {
            const bf16x8 va = *(const bf16x8*)&Vs[(m * 16 + l15) * 264 + s * 32 + quad * 8];
            oacc[m] = __builtin_amdgcn_mfma_f32_16x16x32_bf16(va, pb, oacc[m], 0, 0, 0);
        }
    }
    __builtin_amdgcn_s_setprio(0);

    const float inv = 1.0f / l_sum;
    bf16* op = o + ((size_t)(b * HW + qrow)) * 512 + h * 64 + quad * 4;
    #pragma unroll
    for (int m = 0; m < 4; ++m) {
        bf16x4 ov;
        #pragma unroll
        for (int r = 0; r < 4; ++r) ov[r] = (bf16)(oacc[m][r] * inv);
        *(bf16x4*)&op[m * 16] = ov;
    }
}

// ---------------------------------------------------------------------------
// Residual + LayerNorm + transpose, single global read.
// ---------------------------------------------------------------------------
__global__ __launch_bounds__(256) void ln_kernel(
    const bf16* __restrict__ proj, const bf16* __restrict__ imgb,
    const float* __restrict__ gamma, const float* __restrict__ beta,
    float* __restrict__ out)
{
    const int b  = blockIdx.y;
    const int s0 = blockIdx.x * 32;
    const int tid = threadIdx.x;
    const int wave = tid >> 6, lane = tid & 63;

    __shared__ float Y[32][513];

    const int cb = lane * 8;
    const float4 g0 = *(const float4*)(gamma + cb);
    const float4 g1 = *(const float4*)(gamma + cb + 4);
    const float4 b0 = *(const float4*)(beta + cb);
    const float4 b1 = *(const float4*)(beta + cb + 4);
    const float gg[8] = {g0.x, g0.y, g0.z, g0.w, g1.x, g1.y, g1.z, g1.w};
    const float bb[8] = {b0.x, b0.y, b0.z, b0.w, b1.x, b1.y, b1.z, b1.w};

    #pragma unroll
    for (int rr = 0; rr < 8; ++rr) {
        const int ss = wave * 8 + rr;
        const size_t row = (size_t)b * HW + s0 + ss;
        bf16x8 p8 = *(const bf16x8*)(proj + row * 512 + cb);
        bf16x8 i8 = *(const bf16x8*)(imgb + row * 512 + cb);
        float y[8];
        float sum = 0.f, sq = 0.f;
        #pragma unroll
        for (int j = 0; j < 8; ++j) {
            y[j] = (float)p8[j] + (float)i8[j];
            sum += y[j]; sq += y[j] * y[j];
        }
        #pragma unroll
        for (int off = 32; off > 0; off >>= 1) {
            sum += __shfl_xor(sum, off, 64);
            sq  += __shfl_xor(sq, off, 64);
        }
        const float mu = sum * (1.f / 512.f);
        const float rs = rsqrtf(sq * (1.f / 512.f) - mu * mu + EPS);
        #pragma unroll
        for (int j = 0; j < 8; ++j)
            Y[ss][cb + j] = (y[j] - mu) * rs * gg[j] + bb[j];
    }
    __syncthreads();

    #pragma unroll
    for (int it = 0; it < 16; ++it) {
        const int idx = it * 256 + tid;      // 0..4095
        const int c = idx >> 3, sseg = (idx & 7) << 2;
        float4 o4;
        o4.x = Y[sseg + 0][c];
        o4.y = Y[sseg + 1][c];
        o4.z = Y[sseg + 2][c];
        o4.w = Y[sseg + 3][c];
        *(float4*)(out + ((size_t)b * CCH + c) * HW + s0 + sseg) = o4;
    }
}

// ---------------------------------------------------------------------------
extern "C" void kernel_launch(void* const* d_in, const int* in_sizes, int n_in,
                              void* d_out, int out_size, void* d_ws, size_t ws_size,
                              hipStream_t stream) {
    const float* img   = (const float*)d_in[0];
    const float* audio = (const float*)d_in[1];
    const float* Wq    = (const float*)d_in[2];
    const float* bq    = (const float*)d_in[3];
    const float* Wk    = (const float*)d_in[4];
    const float* bk    = (const float*)d_in[5];
    const float* Wv    = (const float*)d_in[6];
    const float* bv    = (const float*)d_in[7];
    const float* Wo    = (const float*)d_in[8];
    const float* bo    = (const float*)d_in[9];
    const float* gamma = (const float*)d_in[10];
    const float* beta  = (const float*)d_in[11];

    bf16* wsb    = (bf16*)d_ws;
    bf16* img_bf = wsb;                     // 8388608
    bf16* aud_bf = img_bf + 8388608;        // 2097152
    bf16* wT     = aud_bf + 2097152;        // 4*262144 (q,k,v,o)
    bf16* q_bf   = wT + 1048576;            // 8388608
    bf16* kh_bf  = q_bf + 8388608;          // 2097152  [B][H][256][64]
    bf16* vt_bf  = kh_bf + 2097152;         // 2097152  [B][H][64][256]
    bf16* a_bf   = vt_bf + 2097152;         // 8388608
    bf16* p_bf   = q_bf;                    // alias: q dead after attention

    // 1. All casts/transposes in one dispatch
    prep_kernel<<<dim3(3328), 256, 0, stream>>>(img, audio, Wq, Wk, Wv, Wo,
                                                img_bf, aud_bf, wT);
    // 2. Q + K + V projections in one 768-block dispatch (3 blocks/CU)
    qkv_gemm<<<dim3(768), 256, 0, stream>>>(img_bf, wT, bq, q_bf,
                                            aud_bf, wT + 262144, bk, bv, kh_bf, vt_bf);
    // 3. MFMA attention (XCD-chunked block order, staged V)
    attn_mfma<<<dim3(B_SZ * N_HEADS * (HW / 64)), 256, 0, stream>>>(q_bf, kh_bf, vt_bf, a_bf);
    // 4. Output projection: M=16384, N=512 (XCD-chunked block order)
    gemm_bf16_mfma<<<dim3(512), 256, 0, stream>>>(a_bf, wT + 3 * 262144, bo, p_bf);
    // 5. Residual + LN + transpose
    ln_kernel<<<dim3(32, 16), 256, 0, stream>>>(p_bf, img_bf, gamma, beta, (float*)d_out);
}